// Round 1
// baseline (604.727 us; speedup 1.0000x reference)
//
#include <hip/hip_runtime.h>

#define DD 160
#define HH 160
#define WW 160
#define S (DD*HH*WW)   // 4,096,000 voxels

__device__ __forceinline__ float fmul(float a, float b){ return __fmul_rn(a,b); }
__device__ __forceinline__ float fadd(float a, float b){ return __fadd_rn(a,b); }
__device__ __forceinline__ float fsub(float a, float b){ return __fsub_rn(a,b); }

// ddf0 = (dvf0*(1-w) + dvf1*w) / 32   -- bit-exact replica of reference order
__global__ __launch_bounds__(256) void init_kernel(const float* __restrict__ dvf0,
                                                   const float* __restrict__ dvf1,
                                                   const float* __restrict__ wp,
                                                   float* __restrict__ out) {
    int i = blockIdx.x * 256 + threadIdx.x;
    if (i >= 3 * S) return;
    float w = wp[0];
    float onew = fsub(1.0f, w);
    float v = fadd(fmul(dvf0[i], onew), fmul(dvf1[i], w));
    out[i] = fmul(v, 0.03125f);   // /32, exact power of two
}

// out = in + trilinear_warp(in, in)   (MONAI Warp semantics: zeros padding,
// absolute coords = voxel index + displacement). Tap order matches reference.
__global__ __launch_bounds__(256) void warp_add_kernel(const float* __restrict__ in,
                                                       float* __restrict__ out) {
    int p = blockIdx.x * 256 + threadIdx.x;
    if (p >= S) return;
    int x = p % WW;
    int t = p / WW;
    int y = t % HH;
    int z = t / HH;

    float vd = in[p];
    float vh = in[S + p];
    float vw = in[2 * S + p];

    float cd = fadd((float)z, vd);
    float ch = fadd((float)y, vh);
    float cw = fadd((float)x, vw);

    float d0 = floorf(cd), h0 = floorf(ch), w0 = floorf(cw);
    float fd = fsub(cd, d0), fh = fsub(ch, h0), fw = fsub(cw, w0);
    int d0i = (int)d0, h0i = (int)h0, w0i = (int)w0;

    float acc0 = 0.0f, acc1 = 0.0f, acc2 = 0.0f;
    #pragma unroll
    for (int dd = 0; dd < 2; ++dd) {
        #pragma unroll
        for (int dh = 0; dh < 2; ++dh) {
            #pragma unroll
            for (int dw = 0; dw < 2; ++dw) {
                int di = d0i + dd, hi = h0i + dh, wi = w0i + dw;
                bool valid = (di >= 0) & (di < DD) & (hi >= 0) & (hi < HH)
                           & (wi >= 0) & (wi < WW);
                float wd = dd ? fd : fsub(1.0f, fd);
                float wh = dh ? fh : fsub(1.0f, fh);
                float ww_ = dw ? fw : fsub(1.0f, fw);
                float wgt = fmul(fmul(wd, wh), ww_);
                int dc = min(max(di, 0), DD - 1);
                int hc = min(max(hi, 0), HH - 1);
                int wc = min(max(wi, 0), WW - 1);
                int q = (dc * HH + hc) * WW + wc;
                float v0 = valid ? in[q]         : 0.0f;
                float v1 = valid ? in[S + q]     : 0.0f;
                float v2 = valid ? in[2 * S + q] : 0.0f;
                acc0 = fadd(acc0, fmul(v0, wgt));
                acc1 = fadd(acc1, fmul(v1, wgt));
                acc2 = fadd(acc2, fmul(v2, wgt));
            }
        }
    }
    out[p]         = fadd(vd, acc0);
    out[S + p]     = fadd(vh, acc1);
    out[2 * S + p] = fadd(vw, acc2);
}

// img trilinear warp + cav/cor nearest warp with final ddf.
// out layout: [0,S) img, [S,2S) cav, [2S,3S) cor (all as float)
__global__ __launch_bounds__(256) void final_kernel(const float* __restrict__ ddf,
                                                    const float* __restrict__ image,
                                                    const int* __restrict__ cav,
                                                    const int* __restrict__ cor,
                                                    float* __restrict__ out) {
    int p = blockIdx.x * 256 + threadIdx.x;
    if (p >= S) return;
    int x = p % WW;
    int t = p / WW;
    int y = t % HH;
    int z = t / HH;

    float cd = fadd((float)z, ddf[p]);
    float ch = fadd((float)y, ddf[S + p]);
    float cw = fadd((float)x, ddf[2 * S + p]);

    // trilinear image sample
    float d0 = floorf(cd), h0 = floorf(ch), w0 = floorf(cw);
    float fd = fsub(cd, d0), fh = fsub(ch, h0), fw = fsub(cw, w0);
    int d0i = (int)d0, h0i = (int)h0, w0i = (int)w0;
    float acc = 0.0f;
    #pragma unroll
    for (int dd = 0; dd < 2; ++dd) {
        #pragma unroll
        for (int dh = 0; dh < 2; ++dh) {
            #pragma unroll
            for (int dw = 0; dw < 2; ++dw) {
                int di = d0i + dd, hi = h0i + dh, wi = w0i + dw;
                bool valid = (di >= 0) & (di < DD) & (hi >= 0) & (hi < HH)
                           & (wi >= 0) & (wi < WW);
                float wd = dd ? fd : fsub(1.0f, fd);
                float wh = dh ? fh : fsub(1.0f, fh);
                float ww_ = dw ? fw : fsub(1.0f, fw);
                float wgt = fmul(fmul(wd, wh), ww_);
                int dc = min(max(di, 0), DD - 1);
                int hc = min(max(hi, 0), HH - 1);
                int wc = min(max(wi, 0), WW - 1);
                int q = (dc * HH + hc) * WW + wc;
                float v = valid ? image[q] : 0.0f;
                acc = fadd(acc, fmul(v, wgt));
            }
        }
    }
    out[p] = acc;

    // nearest labels (round half to even, matches jnp.round)
    int di = (int)rintf(cd), hi = (int)rintf(ch), wi = (int)rintf(cw);
    bool valid = (di >= 0) & (di < DD) & (hi >= 0) & (hi < HH)
               & (wi >= 0) & (wi < WW);
    int dc = min(max(di, 0), DD - 1);
    int hc = min(max(hi, 0), HH - 1);
    int wc = min(max(wi, 0), WW - 1);
    int q = (dc * HH + hc) * WW + wc;
    out[S + p]     = valid ? (float)cav[q] : 0.0f;
    out[2 * S + p] = valid ? (float)cor[q] : 0.0f;
}

extern "C" void kernel_launch(void* const* d_in, const int* in_sizes, int n_in,
                              void* d_out, int out_size, void* d_ws, size_t ws_size,
                              hipStream_t stream) {
    const float* dvf0   = (const float*)d_in[0];
    const float* dvf1   = (const float*)d_in[1];
    const float* image  = (const float*)d_in[2];
    const int*   cav    = (const int*)d_in[3];
    const int*   cor    = (const int*)d_in[4];
    const float* w      = (const float*)d_in[5];

    float* out = (float*)d_out;
    float* bufA = out;                    // [0,3S): scratch now, img/cav/cor later
    float* bufB = out + (size_t)3 * S;    // [3S,6S): final ddf lives here

    const int vox_blocks  = (S + 255) / 256;        // 16000
    const int init_blocks = (3 * S + 255) / 256;    // 48000

    init_kernel<<<init_blocks, 256, 0, stream>>>(dvf0, dvf1, w, bufA);
    // 5 scaling-and-squaring steps: A->B->A->B->A->B (final ddf in B = out+3S)
    warp_add_kernel<<<vox_blocks, 256, 0, stream>>>(bufA, bufB);
    warp_add_kernel<<<vox_blocks, 256, 0, stream>>>(bufB, bufA);
    warp_add_kernel<<<vox_blocks, 256, 0, stream>>>(bufA, bufB);
    warp_add_kernel<<<vox_blocks, 256, 0, stream>>>(bufB, bufA);
    warp_add_kernel<<<vox_blocks, 256, 0, stream>>>(bufA, bufB);
    final_kernel<<<vox_blocks, 256, 0, stream>>>(bufB, image, cav, cor, bufA);
}